// Round 16
// baseline (245.634 us; speedup 1.0000x reference)
//
#include <hip/hip_runtime.h>

typedef unsigned short u16;
typedef __attribute__((ext_vector_type(4))) float f32x4;
typedef __attribute__((ext_vector_type(16))) float f32x16;
typedef __attribute__((ext_vector_type(8))) __bf16 bf16x8;
typedef __attribute__((ext_vector_type(2))) __bf16 bf16x2;

#define HEADS 32
#define KV_HEADS 8
#define HD 64
#define SEQ 2048
#define HID 2048
#define NQK 3072  // 2048 (Q) + 512 (K) + 512 (V)
#define QSCALE (0.125f * 1.4426950408889634f)  // exp2-domain softmax
#define OCH 2097152u  // u32s per partial-O chunk (512 b5 * 4 waves * 16 * 64)

#define AS1 __attribute__((address_space(1)))
#define AS3 __attribute__((address_space(3)))

__device__ __forceinline__ u16 f2bf(float f) {
  unsigned u = __float_as_uint(f);
  u += 0x7FFFu + ((u >> 16) & 1u);
  return (u16)(u >> 16);
}

__device__ __forceinline__ unsigned pk2(float a, float b) {
  union { bf16x2 h; unsigned u; } c;
  c.h[0] = (__bf16)a; c.h[1] = (__bf16)b;
  return c.u;
}

__device__ __forceinline__ float bflo(unsigned u) {
  return __uint_as_float(u << 16);
}
__device__ __forceinline__ float bfhi(unsigned u) {
  return __uint_as_float(u & 0xFFFF0000u);
}

__device__ __forceinline__ void load16_to_lds(const void* g, void* l) {
  __builtin_amdgcn_global_load_lds((AS1 void*)(void*)g, (AS3 void*)l, 16, 0, 0);
}

// ---------- fused prep: x fp32->bf16 + all 4 weight transposes --------------
__global__ __launch_bounds__(256) void k_prep(const float* __restrict__ x,
                                              const float* __restrict__ Wq,
                                              const float* __restrict__ Wk,
                                              const float* __restrict__ Wv,
                                              const float* __restrict__ Wo,
                                              u16* __restrict__ xb,
                                              u16* __restrict__ Wqkv,
                                              u16* __restrict__ WoT) {
  __shared__ float tile[32][33];
  int bid = blockIdx.x;
  if (bid < 4096) {
    int i = bid * 256 + threadIdx.x;  // exactly SEQ*HID/4 threads
    float4 v = ((const float4*)x)[i];
    ushort4 o;
    o.x = f2bf(v.x); o.y = f2bf(v.y); o.z = f2bf(v.z); o.w = f2bf(v.w);
    ((ushort4*)xb)[i] = o;
    return;
  }
  const float* in; u16* out; int ldi, cx, cy;
  if (bid < 8192) {
    int b = bid - 4096;
    in = Wq; out = Wqkv; ldi = 2048; cx = b & 63; cy = b >> 6;
  } else if (bid < 9216) {
    int b = bid - 8192;
    in = Wk; out = Wqkv + (size_t)2048 * 2048; ldi = 512; cx = b & 15; cy = b >> 4;
  } else if (bid < 10240) {
    int b = bid - 9216;
    in = Wv; out = Wqkv + (size_t)2560 * 2048; ldi = 512; cx = b & 15; cy = b >> 4;
  } else {
    int b = bid - 10240;
    in = Wo; out = WoT; ldi = 2048; cx = b & 63; cy = b >> 6;
  }
  const int ldo = 2048;
  int c0 = cx * 32, r0 = cy * 32;
  int col = threadIdx.x & 31, rw = threadIdx.x >> 5;
#pragma unroll
  for (int i = 0; i < 4; i++)
    tile[rw + i * 8][col] = in[(size_t)(r0 + rw + i * 8) * ldi + c0 + col];
  __syncthreads();
#pragma unroll
  for (int i = 0; i < 4; i++)
    out[(size_t)(c0 + rw + i * 8) * ldo + r0 + col] = f2bf(tile[col][rw + i * 8]);
}

// ======================= out-proj GEMM (R3 template, verbatim) ==============
__device__ __forceinline__ void stage8(const u16* Ap, const u16* Bp, u16* AsX,
                                       u16* BsX, int tid, int K, int koff) {
#pragma unroll
  for (int i = 0; i < 4; i++) {
    load16_to_lds(Ap + (size_t)(i * 32) * K + koff, AsX + (i * 256 + tid) * 8);
    load16_to_lds(Bp + (size_t)(i * 32) * K + koff, BsX + (i * 256 + tid) * 8);
  }
}

__device__ __forceinline__ void frag16(const u16* Asb, const u16* Bsb,
                                       const int aoff[4][2], const int boff[4][2],
                                       f32x4 acc[4][4]) {
#pragma unroll
  for (int kk = 0; kk < 2; kk++) {
    bf16x8 a[4], b[4];
#pragma unroll
    for (int i = 0; i < 4; i++)
      a[i] = *(const bf16x8*)((const char*)Asb + aoff[i][kk]);
#pragma unroll
    for (int j = 0; j < 4; j++)
      b[j] = *(const bf16x8*)((const char*)Bsb + boff[j][kk]);
#pragma unroll
    for (int i = 0; i < 4; i++)
#pragma unroll
      for (int j = 0; j < 4; j++)
        acc[i][j] = __builtin_amdgcn_mfma_f32_16x16x32_bf16(a[i], b[j], acc[i][j], 0, 0, 0);
  }
}

#define TILE_STEP(AsX, BsX, tnext)                              \
  do {                                                          \
    asm volatile("s_waitcnt vmcnt(8)" ::: "memory");            \
    __builtin_amdgcn_sched_barrier(0);                          \
    __builtin_amdgcn_s_barrier();                               \
    frag16(AsX, BsX, aoff, boff, acc);                          \
    __builtin_amdgcn_sched_barrier(0);                          \
    __builtin_amdgcn_s_barrier();                               \
    stage8(Ap, Bp, AsX, BsX, tid, K, (tnext) * 64);             \
    __builtin_amdgcn_sched_barrier(0);                          \
  } while (0)

#define TILE_TAIL(AsX, BsX, n)                                  \
  do {                                                          \
    asm volatile("s_waitcnt vmcnt(" #n ")" ::: "memory");       \
    __builtin_amdgcn_sched_barrier(0);                          \
    __builtin_amdgcn_s_barrier();                               \
    frag16(AsX, BsX, aoff, boff, acc);                          \
  } while (0)

__global__ __launch_bounds__(256) void k_gemm(const u16* __restrict__ A,
                                              const u16* __restrict__ Bt,
                                              float* __restrict__ C,
                                              int M, int N, int K) {
  __shared__ u16 smem[32768];  // 64KB: 2 x (A 16KB + B 16KB)
  u16* As0 = smem;          u16* As1 = smem + 8192;
  u16* Bs0 = smem + 16384;  u16* Bs1 = smem + 24576;
  int tid = threadIdx.x;
  int m0 = blockIdx.x * 128, n0 = blockIdx.y * 128;
  int l = tid & 63, w = tid >> 6;
  int lr = l & 15, lg = l >> 4;
  int wr = (w >> 1) * 64, wc = (w & 1) * 64;
  f32x4 acc[4][4] = {};
  int r8 = tid >> 3;
  int sx = (tid & 7) ^ (r8 & 7);
  const u16* Ap = A + (size_t)(m0 + r8) * K + sx * 8;
  const u16* Bp = Bt + (size_t)(n0 + r8) * K + sx * 8;
  int aoff[4][2], boff[4][2];
#pragma unroll
  for (int i = 0; i < 4; i++) {
    int ra = wr + i * 16 + lr;
    int rb = wc + i * 16 + lr;
#pragma unroll
    for (int kk = 0; kk < 2; kk++) {
      aoff[i][kk] = ra * 128 + (((lg + kk * 4) ^ (ra & 7)) << 4);
      boff[i][kk] = rb * 128 + (((lg + kk * 4) ^ (rb & 7)) << 4);
    }
  }
  stage8(Ap, Bp, As0, Bs0, tid, K, 0);
  stage8(Ap, Bp, As1, Bs1, tid, K, 64);
#pragma unroll 1
  for (int t = 0; t < 30; t += 2) {
    TILE_STEP(As0, Bs0, t + 2);
    TILE_STEP(As1, Bs1, t + 3);
  }
  TILE_TAIL(As0, Bs0, 8);
  TILE_TAIL(As1, Bs1, 0);

#pragma unroll
  for (int i = 0; i < 4; i++)
#pragma unroll
    for (int j = 0; j < 4; j++)
#pragma unroll
      for (int r = 0; r < 4; r++)
        C[(size_t)(m0 + wr + i * 16 + lg * 4 + r) * N + n0 + wc + j * 16 + lr] =
            acc[i][j][r];
}

// ======================= QKV GEMM (R9 config + flag zeroing) ================
__device__ __forceinline__ void stageQ(const u16* Ap, const u16* Bp, u16* S,
                                       int tid, int koff) {
#pragma unroll
  for (int i = 0; i < 2; i++)
    load16_to_lds(Ap + (size_t)(i * 32) * HID + koff, S + (i * 256 + tid) * 8);
#pragma unroll
  for (int i = 0; i < 6; i++)
    load16_to_lds(Bp + (size_t)(i * 32) * HID + koff, S + 4096 + (i * 256 + tid) * 8);
}

__device__ __forceinline__ void frag26(const u16* Sb, const int aoff[2][2],
                                       const int boff[6][2], f32x4 acc[2][6]) {
#pragma unroll
  for (int kk = 0; kk < 2; kk++) {
    bf16x8 a[2], b[6];
#pragma unroll
    for (int i = 0; i < 2; i++)
      a[i] = *(const bf16x8*)((const char*)Sb + aoff[i][kk]);
#pragma unroll
    for (int j = 0; j < 6; j++)
      b[j] = *(const bf16x8*)((const char*)Sb + 8192 + boff[j][kk]);
    __builtin_amdgcn_s_setprio(1);
#pragma unroll
    for (int i = 0; i < 2; i++)
#pragma unroll
      for (int j = 0; j < 6; j++)
        acc[i][j] = __builtin_amdgcn_mfma_f32_16x16x32_bf16(a[i], b[j], acc[i][j], 0, 0, 0);
    __builtin_amdgcn_s_setprio(0);
  }
}

#define QK_STEP(Sc, tnext)                                      \
  do {                                                          \
    asm volatile("s_waitcnt vmcnt(8)" ::: "memory");            \
    __builtin_amdgcn_sched_barrier(0);                          \
    __builtin_amdgcn_s_barrier();                               \
    frag26(Sc, aoff, boff, acc);                                \
    __builtin_amdgcn_sched_barrier(0);                          \
    __builtin_amdgcn_s_barrier();                               \
    stageQ(Ap, Bp, Sc, tid, (tnext) * 64);                      \
    __builtin_amdgcn_sched_barrier(0);                          \
  } while (0)

#define QK_TAIL(Sc, n)                                          \
  do {                                                          \
    asm volatile("s_waitcnt vmcnt(" #n ")" ::: "memory");       \
    __builtin_amdgcn_sched_barrier(0);                          \
    __builtin_amdgcn_s_barrier();                               \
    frag26(Sc, aoff, boff, acc);                                \
  } while (0)

__global__ __launch_bounds__(256) void k_gemm_qkv(const u16* __restrict__ A,
                                                  const u16* __restrict__ Bt,
                                                  const float* __restrict__ cosp,
                                                  const float* __restrict__ sinp,
                                                  u16* __restrict__ qbuf,
                                                  u16* __restrict__ kbuf,
                                                  u16* __restrict__ vtb,
                                                  unsigned* __restrict__ flags) {
  __shared__ u16 smem[32768];  // 64KB: 2 sets x (A 8KB + B 24KB)
  u16* S0 = smem;              // set 0
  u16* S1 = smem + 16384;      // set 1
  u16* Ts = smem;              // 24KB: 192 cols x 64 rows x 2B (V epilogue)
  int tid = threadIdx.x;
  // zero the 512 flash merge-flags (visible to k_flash2 via kernel boundary)
  if (blockIdx.x == 0) {
    flags[tid] = 0;
    flags[tid + 256] = 0;
  }
  // XCD swizzle: grid 512 (32m x 16n); XCD (= bid%8 heuristic) owns 2 B-panels
  int bid = blockIdx.x;
  int wg = (bid & 7) * 64 + (bid >> 3);
  int m0 = (wg & 31) * 64, n0 = (wg >> 5) * 192;
  int l = tid & 63, w = tid >> 6;
  int lr = l & 15, lg = l >> 4;
  int wr = (w >> 1) * 32, wc = (w & 1) * 96;
  f32x4 acc[2][6] = {};
  int r8 = tid >> 3;
  int sx = (tid & 7) ^ (r8 & 7);
  const u16* Ap = A + (size_t)(m0 + r8) * HID + sx * 8;
  const u16* Bp = Bt + (size_t)(n0 + r8) * HID + sx * 8;
  int aoff[2][2], boff[6][2];
#pragma unroll
  for (int i = 0; i < 2; i++) {
    int ra = wr + i * 16 + lr;
#pragma unroll
    for (int kk = 0; kk < 2; kk++)
      aoff[i][kk] = ra * 128 + (((lg + kk * 4) ^ (ra & 7)) << 4);
  }
#pragma unroll
  for (int j = 0; j < 6; j++) {
    int rb = wc + j * 16 + lr;
#pragma unroll
    for (int kk = 0; kk < 2; kk++)
      boff[j][kk] = rb * 128 + (((lg + kk * 4) ^ (rb & 7)) << 4);
  }

  stageQ(Ap, Bp, S0, tid, 0);
  stageQ(Ap, Bp, S1, tid, 64);
#pragma unroll 1
  for (int t = 0; t < 30; t += 2) {
    QK_STEP(S0, t + 2);
    QK_STEP(S1, t + 3);
  }
  QK_TAIL(S0, 8);
  QK_TAIL(S1, 0);

  // ---- epilogue: per-fragment Q/K RoPE stores; V via Ts transpose ----
  int odd = lr & 1;
#pragma unroll
  for (int j = 0; j < 6; j++) {
    int colf = n0 + wc + j * 16;  // wave-uniform, multiple of 16
    if (colf < 2560) {
      bool isQ = colf < 2048;
      float scale = isQ ? QSCALE : 1.0f;
      u16* base = isQ ? qbuf + (size_t)(colf >> 6) * SEQ * HD
                      : kbuf + (size_t)((colf - 2048) >> 6) * SEQ * HD;
      int ch = colf & 63;              // col-in-head base (multiple of 16)
      int ii = (ch >> 1) + (lr >> 1);  // RoPE pair index within head
#pragma unroll
      for (int i = 0; i < 2; i++)
#pragma unroll
        for (int r = 0; r < 4; r++) {
          float v = acc[i][j][r];
          float vp = __shfl_xor(v, 1, 64);
          int sr = m0 + wr + i * 16 + lg * 4 + r;
          float cs = cosp[sr * 32 + ii], sn = sinp[sr * 32 + ii];
          float x1 = odd ? vp : v, x2 = odd ? v : vp;
          float o = odd ? (x1 * sn + x2 * cs) : (x1 * cs - x2 * sn);
          base[(size_t)sr * HD + ch + lr] = f2bf(o * scale);
        }
    }
  }
  if (n0 + 192 > 2560) {  // block contains V columns
    __syncthreads();      // all waves done with pipeline LDS
#pragma unroll
    for (int j = 0; j < 6; j++) {
      int colf = n0 + wc + j * 16;
      if (colf >= 2560) {
#pragma unroll
        for (int i = 0; i < 2; i++)
#pragma unroll
          for (int r = 0; r < 4; r++) {
            int cB = wc + j * 16 + lr, rB = wr + i * 16 + lg * 4 + r;
            *(u16*)((char*)Ts + cB * 128 + ((rB * 2) ^ ((cB & 7) << 4))) =
                f2bf(acc[i][j][r]);
          }
      }
    }
    __syncthreads();
    int half = tid & 1;
#pragma unroll
    for (int p = 0; p < 2; p++) {
      int c = p * 128 + (tid >> 1);
      if (c < 192 && n0 + c >= 2560) {
        int col = n0 + c;
        int kvh = (col - 2560) >> 6, d = col & 63;
        u16* dst = vtb + (size_t)kvh * HD * SEQ + (size_t)d * SEQ + m0 + half * 32;
        const char* src = (const char*)Ts + c * 128;
        int cs7 = (c & 7) << 4;
#pragma unroll
        for (int q = 0; q < 4; q++)
          *(uint4*)(dst + q * 8) = *(const uint4*)(src + ((half * 64 + q * 16) ^ cs7));
      }
    }
  }
}

// ---------- Flash attention (R16): KV-split x2 + fused second-finisher merge
// Grid 1024 = 2 chunks x 512 b5 (measured best flash topology).  Each block
// stores its partial O + (m,l), releases via device fence, then thread 0
// does an agent-scope acq_rel fetch_add on flags[b5].  The SECOND finisher
// (old==1) acquires (invalidates caches -> sees the loser's L2-released
// partials even cross-XCD) and runs the merge inline: combine both chunks,
// normalize, LDS-transpose (reusing Ks), write av.  Removes the k_merge
// launch + its cold 17MB re-read.
__global__ __launch_bounds__(256) void k_flash2(const u16* __restrict__ qb,
                                                const u16* __restrict__ kb,
                                                const u16* __restrict__ vt,
                                                unsigned* __restrict__ Opart,
                                                float2* __restrict__ ml,
                                                u16* __restrict__ av,
                                                unsigned* __restrict__ flags) {
  __shared__ u16 Ks[2][64 * 64];
  __shared__ u16 Vs[2][64 * 64];
  __shared__ unsigned winner;
  int bid = blockIdx.x;
  int c = bid & 1;                  // chunk fastest
  int b5 = bid >> 1;                // 0..511
  int h = b5 & 31;                  // heads next
  int qi = b5 >> 5;
  int qblk = (SEQ / 128) - 1 - qi;  // LPT: heaviest first
  int kvh = h & 7;
  int tid = threadIdx.x, w = tid >> 6, l = tid & 63;
  int lq = l & 31, hi = l >> 5;
  const u16* qh = qb + (size_t)h * SEQ * HD;
  const u16* kh = kb + (size_t)kvh * SEQ * HD;
  const u16* vh = vt + (size_t)kvh * HD * SEQ;
  int wq0 = qblk * 128 + w * 32;
  int qg = wq0 + lq;

  bf16x8 qf[4];
#pragma unroll
  for (int ds = 0; ds < 4; ds++)
    qf[ds] = *(const bf16x8*)(qh + (size_t)qg * HD + ds * 16 + hi * 8);

  f32x16 acc[2] = {};   // O^T: lane: q=l&31, d = dt*32 + (r&3)+8*(r>>2)+4*hi
  float m_r = -__builtin_inff(), l_r = 0.f;

  int srow = tid >> 2, c4 = tid & 3, swz = (srow & 7) << 4;
  int sd0 = srow * 128 + ((c4 * 32) ^ swz);
  int sd1 = srow * 128 + ((c4 * 32 + 16) ^ swz);
  const int kt0 = c * (qblk + 1), kt1 = kt0 + qblk + 1;

  // prologue: stage tile kt0
  {
    const u16* ksrc = kh + (size_t)(kt0 * 64 + srow) * HD + c4 * 16;
    const u16* vsrc = vh + (size_t)srow * SEQ + kt0 * 64 + c4 * 16;
    uint4 a0 = *(const uint4*)(ksrc), a1 = *(const uint4*)(ksrc + 8);
    uint4 b0 = *(const uint4*)(vsrc), b1 = *(const uint4*)(vsrc + 8);
    *(uint4*)((char*)Ks[0] + sd0) = a0; *(uint4*)((char*)Ks[0] + sd1) = a1;
    *(uint4*)((char*)Vs[0] + sd0) = b0; *(uint4*)((char*)Vs[0] + sd1) = b1;
  }
  __syncthreads();

  uint4 kr0, kr1, vr0, vr1;
  int lswz = (lq & 7) << 4;
  for (int kt = kt0; kt < kt1; kt++) {
    int b = (kt - kt0) & 1;
    if (kt + 1 < kt1) {
      const u16* ksrc = kh + (size_t)((kt + 1) * 64 + srow) * HD + c4 * 16;
      const u16* vsrc = vh + (size_t)srow * SEQ + (kt + 1) * 64 + c4 * 16;
      kr0 = *(const uint4*)(ksrc); kr1 = *(const uint4*)(ksrc + 8);
      vr0 = *(const uint4*)(vsrc); vr1 = *(const uint4*)(vsrc + 8);
    }

    if (kt * 64 <= wq0 + 31) {  // skip fully-masked tiles
      f32x16 sT[2] = {};
      const char* kbase = (const char*)Ks[b];
      __builtin_amdgcn_s_setprio(1);
#pragma unroll
      for (int t = 0; t < 2; t++) {
#pragma unroll
        for (int ds = 0; ds < 4; ds++) {
          bf16x8 kf = *(const bf16x8*)(kbase + (t * 32 + lq) * 128 +
                                       ((ds * 32 + hi * 16) ^ lswz));
          sT[t] = __builtin_amdgcn_mfma_f32_32x32x16_bf16(kf, qf[ds], sT[t], 0, 0, 0);
        }
      }
      __builtin_amdgcn_s_setprio(0);

      if (kt * 64 + 63 > wq0) {
#pragma unroll
        for (int t = 0; t < 2; t++)
#pragma unroll
          for (int r = 0; r < 16; r++) {
            int kg = kt * 64 + t * 32 + (r & 3) + 8 * (r >> 2) + 4 * hi;
            if (kg > qg) sT[t][r] = -__builtin_inff();
          }
      }

      float pmax = sT[0][0];
#pragma unroll
      for (int r = 1; r < 16; r++) pmax = fmaxf(pmax, sT[0][r]);
#pragma unroll
      for (int r = 0; r < 16; r++) pmax = fmaxf(pmax, sT[1][r]);
      pmax = fmaxf(pmax, __shfl_xor(pmax, 32, 64));

      if (!__all(pmax <= m_r + 8.f)) {
        float mn = fmaxf(m_r, pmax);
        float scl = __builtin_amdgcn_exp2f(m_r - mn);
        l_r *= scl;
        acc[0] *= scl;
        acc[1] *= scl;
        m_r = mn;
      }

      float ss = 0.f;
#pragma unroll
      for (int t = 0; t < 2; t++)
#pragma unroll
        for (int r = 0; r < 16; r++) {
          float p = __builtin_amdgcn_exp2f(sT[t][r] - m_r);
          sT[t][r] = p;
          ss += p;
        }
      ss += __shfl_xor(ss, 32, 64);
      l_r += ss;

      const char* vbase = (const char*)Vs[b];
#pragma unroll
      for (int t = 0; t < 2; t++) {
        unsigned cp[4][2];
#pragma unroll
        for (int m = 0; m < 4; m++) {
          cp[m][0] = pk2(sT[t][4 * m + 0], sT[t][4 * m + 1]);
          cp[m][1] = pk2(sT[t][4 * m + 2], sT[t][4 * m + 3]);
        }
#pragma unroll
        for (int kl = 0; kl < 2; kl++) {
          unsigned s0 = hi ? cp[2 * kl][0] : cp[2 * kl + 1][0];
          unsigned s1 = hi ? cp[2 * kl][1] : cp[2 * kl + 1][1];
          unsigned r0 = (unsigned)__shfl_xor((int)s0, 32, 64);
          unsigned r1 = (unsigned)__shfl_xor((int)s1, 32, 64);
          union { unsigned u[4]; bf16x8 v; } pa;
          pa.u[0] = hi ? r0 : cp[2 * kl][0];
          pa.u[1] = hi ? r1 : cp[2 * kl][1];
          pa.u[2] = hi ? cp[2 * kl + 1][0] : r0;
          pa.u[3] = hi ? cp[2 * kl + 1][1] : r1;
          int ks = t * 2 + kl;
          __builtin_amdgcn_s_setprio(1);
#pragma unroll
          for (int dt = 0; dt < 2; dt++) {
            bf16x8 vb = *(const bf16x8*)(vbase + (dt * 32 + lq) * 128 +
                                         ((ks * 32 + hi * 16) ^ lswz));
            acc[dt] = __builtin_amdgcn_mfma_f32_32x32x16_bf16(vb, pa.v, acc[dt], 0, 0, 0);
          }
          __builtin_amdgcn_s_setprio(0);
        }
      }
    }

    if (kt + 1 < kt1) {
      *(uint4*)((char*)Ks[b ^ 1] + sd0) = kr0;
      *(uint4*)((char*)Ks[b ^ 1] + sd1) = kr1;
      *(uint4*)((char*)Vs[b ^ 1] + sd0) = vr0;
      *(uint4*)((char*)Vs[b ^ 1] + sd1) = vr1;
    }
    __syncthreads();
  }

  // epilogue: dump raw-lane-layout partial O (bf16 pairs) + (m,l), coalesced
  unsigned* op = Opart + (size_t)c * OCH + ((size_t)(b5 * 4 + w) * 16) * 64;
#pragma unroll
  for (int dt = 0; dt < 2; dt++)
#pragma unroll
    for (int j = 0; j < 8; j++)
      op[(dt * 8 + j) * 64 + l] = pk2(acc[dt][2 * j], acc[dt][2 * j + 1]);
  if (!hi)
    ml[c * (HEADS * SEQ) + h * SEQ + wq0 + lq] = make_float2(m_r, l_r);

  // ---- fused merge: second finisher of the (b5) pair combines both chunks --
  __threadfence();   // release own partials to device scope (all waves)
  __syncthreads();   // all waves fenced before the flag bump
  if (tid == 0)
    winner = __hip_atomic_fetch_add(&flags[b5], 1u, __ATOMIC_ACQ_REL,
                                    __HIP_MEMORY_SCOPE_AGENT);
  __syncthreads();
  if (winner == 1) {  // block-uniform: we finished second -> merge
    float2 ml0 = ml[h * SEQ + wq0 + lq];
    float2 ml1 = ml[HEADS * SEQ + h * SEQ + wq0 + lq];
    float mm = fmaxf(ml0.x, ml1.x);
    float f0 = __builtin_amdgcn_exp2f(ml0.x - mm);
    float f1 = __builtin_amdgcn_exp2f(ml1.x - mm);
    float inv = 1.0f / (ml0.y * f0 + ml1.y * f1);

    const unsigned* mop0 = Opart + ((size_t)(b5 * 4 + w) * 16) * 64;
    const unsigned* mop1 = mop0 + OCH;
    f32x16 macc[2];
#pragma unroll
    for (int dt = 0; dt < 2; dt++)
#pragma unroll
      for (int j = 0; j < 8; j++) {
        unsigned a0 = mop0[(dt * 8 + j) * 64 + l];
        unsigned a1 = mop1[(dt * 8 + j) * 64 + l];
        macc[dt][2 * j] = bflo(a0) * f0 + bflo(a1) * f1;
        macc[dt][2 * j + 1] = bfhi(a0) * f0 + bfhi(a1) * f1;
      }

    // LDS transpose epilogue (Ts reuses Ks: flash loop is done)
    char* wbase = (char*)Ks[0] + w * 4096;  // 4 waves x 4KB
#pragma unroll
    for (int dt = 0; dt < 2; dt++)
#pragma unroll
      for (int m4 = 0; m4 < 4; m4++) {
        int r0 = 4 * m4;
        uint2 pr;
        pr.x = pk2(macc[dt][r0 + 0] * inv, macc[dt][r0 + 1] * inv);
        pr.y = pk2(macc[dt][r0 + 2] * inv, macc[dt][r0 + 3] * inv);
        int byte = lq * 128 + ((dt * 64 + m4 * 16 + hi * 8) ^ lswz);
        *(uint2*)(wbase + byte) = pr;
      }
    __syncthreads();
    int q2 = l >> 1, cH = l & 1;
    int qswz = (q2 & 7) << 4;
#pragma unroll
    for (int i = 0; i < 4; i++) {
      uint4 d = *(const uint4*)(wbase + q2 * 128 + ((cH * 64 + i * 16) ^ qswz));
      *(uint4*)(av + (size_t)(wq0 + q2) * HID + h * HD + cH * 32 + i * 8) = d;
    }
  }
}

extern "C" void kernel_launch(void* const* d_in, const int* in_sizes, int n_in,
                              void* d_out, int out_size, void* d_ws, size_t ws_size,
                              hipStream_t stream) {
  (void)in_sizes; (void)n_in; (void)out_size; (void)ws_size;
  const float* x = (const float*)d_in[0];
  const float* cosp = (const float*)d_in[1];
  const float* sinp = (const float*)d_in[2];
  const float* Wq = (const float*)d_in[3];
  const float* Wk = (const float*)d_in[4];
  const float* Wv = (const float*)d_in[5];
  const float* Wo = (const float*)d_in[6];
  float* out = (float*)d_out;
  char* ws = (char*)d_ws;

  // workspace layout (64 MiB):
  u16* xb = (u16*)(ws);                          // [0,8M)   x bf16; dead after qkv
  float2* mlb = (float2*)(ws);                   // [0,1M)   aliases dead xb (flash2+)
  u16* Wqkv = (u16*)(ws + ((size_t)8 << 20));    // [8,20M)  Wq^T|Wk^T|Wv^T
  u16* WoT = (u16*)(ws + ((size_t)20 << 20));    // [20,28M) Wo^T
  u16* qbuf = (u16*)(ws + ((size_t)28 << 20));   // [28,36M) q rope bf16 [32][S][64]
  u16* kbuf = (u16*)(ws + ((size_t)36 << 20));   // [36,38M) k rope bf16 [8][S][64]
  u16* vtb = (u16*)(ws + ((size_t)38 << 20));    // [38,40M) v^T bf16 [8][64][S]
  u16* av = (u16*)(ws + ((size_t)40 << 20));     // [40,48M) av bf16 [S][2048]
  unsigned* Opart = (unsigned*)(ws + ((size_t)48 << 20));  // [48,64M) 2 chunks x 8M
  // merge flags: first 2KB of d_out (dead until out-proj overwrites all of C)
  unsigned* flags = (unsigned*)out;

  k_prep<<<14336, 256, 0, stream>>>(x, Wq, Wk, Wv, Wo, xb, Wqkv, WoT);
  k_gemm_qkv<<<512, 256, 0, stream>>>(xb, Wqkv, cosp, sinp, qbuf, kbuf, vtb, flags);
  k_flash2<<<(SEQ / 128) * HEADS * 2, 256, 0, stream>>>(qbuf, kbuf, vtb, Opart,
                                                        mlb, av, flags);
  k_gemm<<<dim3(SEQ / 128, HID / 128), 256, 0, stream>>>(av, WoT, out, SEQ, HID, HID);
}

// Round 17
// 115.917 us; speedup vs baseline: 2.1191x; 2.1191x over previous
//
#include <hip/hip_runtime.h>

typedef unsigned short u16;
typedef __attribute__((ext_vector_type(4))) float f32x4;
typedef __attribute__((ext_vector_type(16))) float f32x16;
typedef __attribute__((ext_vector_type(8))) __bf16 bf16x8;
typedef __attribute__((ext_vector_type(2))) __bf16 bf16x2;

#define HEADS 32
#define KV_HEADS 8
#define HD 64
#define SEQ 2048
#define HID 2048
#define NQK 3072  // 2048 (Q) + 512 (K) + 512 (V)
#define QSCALE (0.125f * 1.4426950408889634f)  // exp2-domain softmax
#define OCH 2097152u  // u32s per partial-O chunk (512 b5 * 4 waves * 16 * 64)

#define AS1 __attribute__((address_space(1)))
#define AS3 __attribute__((address_space(3)))

__device__ __forceinline__ u16 f2bf(float f) {
  unsigned u = __float_as_uint(f);
  u += 0x7FFFu + ((u >> 16) & 1u);
  return (u16)(u >> 16);
}

__device__ __forceinline__ unsigned pk2(float a, float b) {
  union { bf16x2 h; unsigned u; } c;
  c.h[0] = (__bf16)a; c.h[1] = (__bf16)b;
  return c.u;
}

__device__ __forceinline__ float bflo(unsigned u) {
  return __uint_as_float(u << 16);
}
__device__ __forceinline__ float bfhi(unsigned u) {
  return __uint_as_float(u & 0xFFFF0000u);
}

__device__ __forceinline__ void load16_to_lds(const void* g, void* l) {
  __builtin_amdgcn_global_load_lds((AS1 void*)(void*)g, (AS3 void*)l, 16, 0, 0);
}

// ---------- fused prep: x fp32->bf16 + all 4 weight transposes --------------
__global__ __launch_bounds__(256) void k_prep(const float* __restrict__ x,
                                              const float* __restrict__ Wq,
                                              const float* __restrict__ Wk,
                                              const float* __restrict__ Wv,
                                              const float* __restrict__ Wo,
                                              u16* __restrict__ xb,
                                              u16* __restrict__ Wqkv,
                                              u16* __restrict__ WoT) {
  __shared__ float tile[32][33];
  int bid = blockIdx.x;
  if (bid < 4096) {
    int i = bid * 256 + threadIdx.x;  // exactly SEQ*HID/4 threads
    float4 v = ((const float4*)x)[i];
    ushort4 o;
    o.x = f2bf(v.x); o.y = f2bf(v.y); o.z = f2bf(v.z); o.w = f2bf(v.w);
    ((ushort4*)xb)[i] = o;
    return;
  }
  const float* in; u16* out; int ldi, cx, cy;
  if (bid < 8192) {
    int b = bid - 4096;
    in = Wq; out = Wqkv; ldi = 2048; cx = b & 63; cy = b >> 6;
  } else if (bid < 9216) {
    int b = bid - 8192;
    in = Wk; out = Wqkv + (size_t)2048 * 2048; ldi = 512; cx = b & 15; cy = b >> 4;
  } else if (bid < 10240) {
    int b = bid - 9216;
    in = Wv; out = Wqkv + (size_t)2560 * 2048; ldi = 512; cx = b & 15; cy = b >> 4;
  } else {
    int b = bid - 10240;
    in = Wo; out = WoT; ldi = 2048; cx = b & 63; cy = b >> 6;
  }
  const int ldo = 2048;
  int c0 = cx * 32, r0 = cy * 32;
  int col = threadIdx.x & 31, rw = threadIdx.x >> 5;
#pragma unroll
  for (int i = 0; i < 4; i++)
    tile[rw + i * 8][col] = in[(size_t)(r0 + rw + i * 8) * ldi + c0 + col];
  __syncthreads();
#pragma unroll
  for (int i = 0; i < 4; i++)
    out[(size_t)(c0 + rw + i * 8) * ldo + r0 + col] = f2bf(tile[col][rw + i * 8]);
}

// ======================= out-proj GEMM (R3 template, verbatim) ==============
__device__ __forceinline__ void stage8(const u16* Ap, const u16* Bp, u16* AsX,
                                       u16* BsX, int tid, int K, int koff) {
#pragma unroll
  for (int i = 0; i < 4; i++) {
    load16_to_lds(Ap + (size_t)(i * 32) * K + koff, AsX + (i * 256 + tid) * 8);
    load16_to_lds(Bp + (size_t)(i * 32) * K + koff, BsX + (i * 256 + tid) * 8);
  }
}

__device__ __forceinline__ void frag16(const u16* Asb, const u16* Bsb,
                                       const int aoff[4][2], const int boff[4][2],
                                       f32x4 acc[4][4]) {
#pragma unroll
  for (int kk = 0; kk < 2; kk++) {
    bf16x8 a[4], b[4];
#pragma unroll
    for (int i = 0; i < 4; i++)
      a[i] = *(const bf16x8*)((const char*)Asb + aoff[i][kk]);
#pragma unroll
    for (int j = 0; j < 4; j++)
      b[j] = *(const bf16x8*)((const char*)Bsb + boff[j][kk]);
#pragma unroll
    for (int i = 0; i < 4; i++)
#pragma unroll
      for (int j = 0; j < 4; j++)
        acc[i][j] = __builtin_amdgcn_mfma_f32_16x16x32_bf16(a[i], b[j], acc[i][j], 0, 0, 0);
  }
}

#define TILE_STEP(AsX, BsX, tnext)                              \
  do {                                                          \
    asm volatile("s_waitcnt vmcnt(8)" ::: "memory");            \
    __builtin_amdgcn_sched_barrier(0);                          \
    __builtin_amdgcn_s_barrier();                               \
    frag16(AsX, BsX, aoff, boff, acc);                          \
    __builtin_amdgcn_sched_barrier(0);                          \
    __builtin_amdgcn_s_barrier();                               \
    stage8(Ap, Bp, AsX, BsX, tid, K, (tnext) * 64);             \
    __builtin_amdgcn_sched_barrier(0);                          \
  } while (0)

#define TILE_TAIL(AsX, BsX, n)                                  \
  do {                                                          \
    asm volatile("s_waitcnt vmcnt(" #n ")" ::: "memory");       \
    __builtin_amdgcn_sched_barrier(0);                          \
    __builtin_amdgcn_s_barrier();                               \
    frag16(AsX, BsX, aoff, boff, acc);                          \
  } while (0)

__global__ __launch_bounds__(256) void k_gemm(const u16* __restrict__ A,
                                              const u16* __restrict__ Bt,
                                              float* __restrict__ C,
                                              int M, int N, int K) {
  __shared__ u16 smem[32768];  // 64KB: 2 x (A 16KB + B 16KB)
  u16* As0 = smem;          u16* As1 = smem + 8192;
  u16* Bs0 = smem + 16384;  u16* Bs1 = smem + 24576;
  int tid = threadIdx.x;
  int m0 = blockIdx.x * 128, n0 = blockIdx.y * 128;
  int l = tid & 63, w = tid >> 6;
  int lr = l & 15, lg = l >> 4;
  int wr = (w >> 1) * 64, wc = (w & 1) * 64;
  f32x4 acc[4][4] = {};
  int r8 = tid >> 3;
  int sx = (tid & 7) ^ (r8 & 7);
  const u16* Ap = A + (size_t)(m0 + r8) * K + sx * 8;
  const u16* Bp = Bt + (size_t)(n0 + r8) * K + sx * 8;
  int aoff[4][2], boff[4][2];
#pragma unroll
  for (int i = 0; i < 4; i++) {
    int ra = wr + i * 16 + lr;
    int rb = wc + i * 16 + lr;
#pragma unroll
    for (int kk = 0; kk < 2; kk++) {
      aoff[i][kk] = ra * 128 + (((lg + kk * 4) ^ (ra & 7)) << 4);
      boff[i][kk] = rb * 128 + (((lg + kk * 4) ^ (rb & 7)) << 4);
    }
  }
  stage8(Ap, Bp, As0, Bs0, tid, K, 0);
  stage8(Ap, Bp, As1, Bs1, tid, K, 64);
#pragma unroll 1
  for (int t = 0; t < 30; t += 2) {
    TILE_STEP(As0, Bs0, t + 2);
    TILE_STEP(As1, Bs1, t + 3);
  }
  TILE_TAIL(As0, Bs0, 8);
  TILE_TAIL(As1, Bs1, 0);

#pragma unroll
  for (int i = 0; i < 4; i++)
#pragma unroll
    for (int j = 0; j < 4; j++)
#pragma unroll
      for (int r = 0; r < 4; r++)
        C[(size_t)(m0 + wr + i * 16 + lg * 4 + r) * N + n0 + wc + j * 16 + lr] =
            acc[i][j][r];
}

// ======================= QKV GEMM (R9 config, verbatim — best measured) =====
__device__ __forceinline__ void stageQ(const u16* Ap, const u16* Bp, u16* S,
                                       int tid, int koff) {
#pragma unroll
  for (int i = 0; i < 2; i++)
    load16_to_lds(Ap + (size_t)(i * 32) * HID + koff, S + (i * 256 + tid) * 8);
#pragma unroll
  for (int i = 0; i < 6; i++)
    load16_to_lds(Bp + (size_t)(i * 32) * HID + koff, S + 4096 + (i * 256 + tid) * 8);
}

__device__ __forceinline__ void frag26(const u16* Sb, const int aoff[2][2],
                                       const int boff[6][2], f32x4 acc[2][6]) {
#pragma unroll
  for (int kk = 0; kk < 2; kk++) {
    bf16x8 a[2], b[6];
#pragma unroll
    for (int i = 0; i < 2; i++)
      a[i] = *(const bf16x8*)((const char*)Sb + aoff[i][kk]);
#pragma unroll
    for (int j = 0; j < 6; j++)
      b[j] = *(const bf16x8*)((const char*)Sb + 8192 + boff[j][kk]);
    __builtin_amdgcn_s_setprio(1);
#pragma unroll
    for (int i = 0; i < 2; i++)
#pragma unroll
      for (int j = 0; j < 6; j++)
        acc[i][j] = __builtin_amdgcn_mfma_f32_16x16x32_bf16(a[i], b[j], acc[i][j], 0, 0, 0);
    __builtin_amdgcn_s_setprio(0);
  }
}

#define QK_STEP(Sc, tnext)                                      \
  do {                                                          \
    asm volatile("s_waitcnt vmcnt(8)" ::: "memory");            \
    __builtin_amdgcn_sched_barrier(0);                          \
    __builtin_amdgcn_s_barrier();                               \
    frag26(Sc, aoff, boff, acc);                                \
    __builtin_amdgcn_sched_barrier(0);                          \
    __builtin_amdgcn_s_barrier();                               \
    stageQ(Ap, Bp, Sc, tid, (tnext) * 64);                      \
    __builtin_amdgcn_sched_barrier(0);                          \
  } while (0)

#define QK_TAIL(Sc, n)                                          \
  do {                                                          \
    asm volatile("s_waitcnt vmcnt(" #n ")" ::: "memory");       \
    __builtin_amdgcn_sched_barrier(0);                          \
    __builtin_amdgcn_s_barrier();                               \
    frag26(Sc, aoff, boff, acc);                                \
  } while (0)

__global__ __launch_bounds__(256) void k_gemm_qkv(const u16* __restrict__ A,
                                                  const u16* __restrict__ Bt,
                                                  const float* __restrict__ cosp,
                                                  const float* __restrict__ sinp,
                                                  u16* __restrict__ qbuf,
                                                  u16* __restrict__ kbuf,
                                                  u16* __restrict__ vtb) {
  __shared__ u16 smem[32768];  // 64KB: 2 sets x (A 8KB + B 24KB)
  u16* S0 = smem;              // set 0
  u16* S1 = smem + 16384;      // set 1
  u16* Ts = smem;              // 24KB: 192 cols x 64 rows x 2B (V epilogue)
  int tid = threadIdx.x;
  // XCD swizzle: grid 512 (32m x 16n); XCD (= bid%8 heuristic) owns 2 B-panels
  int bid = blockIdx.x;
  int wg = (bid & 7) * 64 + (bid >> 3);
  int m0 = (wg & 31) * 64, n0 = (wg >> 5) * 192;
  int l = tid & 63, w = tid >> 6;
  int lr = l & 15, lg = l >> 4;
  int wr = (w >> 1) * 32, wc = (w & 1) * 96;
  f32x4 acc[2][6] = {};
  int r8 = tid >> 3;
  int sx = (tid & 7) ^ (r8 & 7);
  const u16* Ap = A + (size_t)(m0 + r8) * HID + sx * 8;
  const u16* Bp = Bt + (size_t)(n0 + r8) * HID + sx * 8;
  int aoff[2][2], boff[6][2];
#pragma unroll
  for (int i = 0; i < 2; i++) {
    int ra = wr + i * 16 + lr;
#pragma unroll
    for (int kk = 0; kk < 2; kk++)
      aoff[i][kk] = ra * 128 + (((lg + kk * 4) ^ (ra & 7)) << 4);
  }
#pragma unroll
  for (int j = 0; j < 6; j++) {
    int rb = wc + j * 16 + lr;
#pragma unroll
    for (int kk = 0; kk < 2; kk++)
      boff[j][kk] = rb * 128 + (((lg + kk * 4) ^ (rb & 7)) << 4);
  }

  stageQ(Ap, Bp, S0, tid, 0);
  stageQ(Ap, Bp, S1, tid, 64);
#pragma unroll 1
  for (int t = 0; t < 30; t += 2) {
    QK_STEP(S0, t + 2);
    QK_STEP(S1, t + 3);
  }
  QK_TAIL(S0, 8);
  QK_TAIL(S1, 0);

  // ---- epilogue: per-fragment Q/K RoPE stores; V via Ts transpose ----
  int odd = lr & 1;
#pragma unroll
  for (int j = 0; j < 6; j++) {
    int colf = n0 + wc + j * 16;  // wave-uniform, multiple of 16
    if (colf < 2560) {
      bool isQ = colf < 2048;
      float scale = isQ ? QSCALE : 1.0f;
      u16* base = isQ ? qbuf + (size_t)(colf >> 6) * SEQ * HD
                      : kbuf + (size_t)((colf - 2048) >> 6) * SEQ * HD;
      int ch = colf & 63;              // col-in-head base (multiple of 16)
      int ii = (ch >> 1) + (lr >> 1);  // RoPE pair index within head
#pragma unroll
      for (int i = 0; i < 2; i++)
#pragma unroll
        for (int r = 0; r < 4; r++) {
          float v = acc[i][j][r];
          float vp = __shfl_xor(v, 1, 64);
          int sr = m0 + wr + i * 16 + lg * 4 + r;
          float cs = cosp[sr * 32 + ii], sn = sinp[sr * 32 + ii];
          float x1 = odd ? vp : v, x2 = odd ? v : vp;
          float o = odd ? (x1 * sn + x2 * cs) : (x1 * cs - x2 * sn);
          base[(size_t)sr * HD + ch + lr] = f2bf(o * scale);
        }
    }
  }
  if (n0 + 192 > 2560) {  // block contains V columns
    __syncthreads();      // all waves done with pipeline LDS
#pragma unroll
    for (int j = 0; j < 6; j++) {
      int colf = n0 + wc + j * 16;
      if (colf >= 2560) {
#pragma unroll
        for (int i = 0; i < 2; i++)
#pragma unroll
          for (int r = 0; r < 4; r++) {
            int cB = wc + j * 16 + lr, rB = wr + i * 16 + lg * 4 + r;
            *(u16*)((char*)Ts + cB * 128 + ((rB * 2) ^ ((cB & 7) << 4))) =
                f2bf(acc[i][j][r]);
          }
      }
    }
    __syncthreads();
    int half = tid & 1;
#pragma unroll
    for (int p = 0; p < 2; p++) {
      int c = p * 128 + (tid >> 1);
      if (c < 192 && n0 + c >= 2560) {
        int col = n0 + c;
        int kvh = (col - 2560) >> 6, d = col & 63;
        u16* dst = vtb + (size_t)kvh * HD * SEQ + (size_t)d * SEQ + m0 + half * 32;
        const char* src = (const char*)Ts + c * 128;
        int cs7 = (c & 7) << 4;
#pragma unroll
        for (int q = 0; q < 4; q++)
          *(uint4*)(dst + q * 8) = *(const uint4*)(src + ((half * 64 + q * 16) ^ cs7));
      }
    }
  }
}

// ---------- Flash attention pass 1 (R11 config): KV-split x2 ----------------
// Grid 1024 = 2 chunks x 512 b5 -> 4 blocks/CU (measured best flash topology:
// x2=~33us < x4=49 < single-pass=66).  Chunk c covers [c*(qblk+1),
// (c+1)*(qblk+1)); dumps unnormalized O^T bf16-pairs + per-row (m,l).
__global__ __launch_bounds__(256) void k_flash2(const u16* __restrict__ qb,
                                                const u16* __restrict__ kb,
                                                const u16* __restrict__ vt,
                                                unsigned* __restrict__ Opart,
                                                float2* __restrict__ ml) {
  __shared__ u16 Ks[2][64 * 64];
  __shared__ u16 Vs[2][64 * 64];
  int bid = blockIdx.x;
  int c = bid & 1;                  // chunk fastest
  int b5 = bid >> 1;                // 0..511
  int h = b5 & 31;                  // heads next
  int qi = b5 >> 5;
  int qblk = (SEQ / 128) - 1 - qi;  // LPT: heaviest first
  int kvh = h & 7;
  int tid = threadIdx.x, w = tid >> 6, l = tid & 63;
  int lq = l & 31, hi = l >> 5;
  const u16* qh = qb + (size_t)h * SEQ * HD;
  const u16* kh = kb + (size_t)kvh * SEQ * HD;
  const u16* vh = vt + (size_t)kvh * HD * SEQ;
  int wq0 = qblk * 128 + w * 32;
  int qg = wq0 + lq;

  bf16x8 qf[4];
#pragma unroll
  for (int ds = 0; ds < 4; ds++)
    qf[ds] = *(const bf16x8*)(qh + (size_t)qg * HD + ds * 16 + hi * 8);

  f32x16 acc[2] = {};   // O^T: lane: q=l&31, d = dt*32 + (r&3)+8*(r>>2)+4*hi
  float m_r = -__builtin_inff(), l_r = 0.f;

  int srow = tid >> 2, c4 = tid & 3, swz = (srow & 7) << 4;
  int sd0 = srow * 128 + ((c4 * 32) ^ swz);
  int sd1 = srow * 128 + ((c4 * 32 + 16) ^ swz);
  const int kt0 = c * (qblk + 1), kt1 = kt0 + qblk + 1;

  // prologue: stage tile kt0
  {
    const u16* ksrc = kh + (size_t)(kt0 * 64 + srow) * HD + c4 * 16;
    const u16* vsrc = vh + (size_t)srow * SEQ + kt0 * 64 + c4 * 16;
    uint4 a0 = *(const uint4*)(ksrc), a1 = *(const uint4*)(ksrc + 8);
    uint4 b0 = *(const uint4*)(vsrc), b1 = *(const uint4*)(vsrc + 8);
    *(uint4*)((char*)Ks[0] + sd0) = a0; *(uint4*)((char*)Ks[0] + sd1) = a1;
    *(uint4*)((char*)Vs[0] + sd0) = b0; *(uint4*)((char*)Vs[0] + sd1) = b1;
  }
  __syncthreads();

  uint4 kr0, kr1, vr0, vr1;
  int lswz = (lq & 7) << 4;
  for (int kt = kt0; kt < kt1; kt++) {
    int b = (kt - kt0) & 1;
    if (kt + 1 < kt1) {
      const u16* ksrc = kh + (size_t)((kt + 1) * 64 + srow) * HD + c4 * 16;
      const u16* vsrc = vh + (size_t)srow * SEQ + (kt + 1) * 64 + c4 * 16;
      kr0 = *(const uint4*)(ksrc); kr1 = *(const uint4*)(ksrc + 8);
      vr0 = *(const uint4*)(vsrc); vr1 = *(const uint4*)(vsrc + 8);
    }

    if (kt * 64 <= wq0 + 31) {  // skip fully-masked tiles
      f32x16 sT[2] = {};
      const char* kbase = (const char*)Ks[b];
      __builtin_amdgcn_s_setprio(1);
#pragma unroll
      for (int t = 0; t < 2; t++) {
#pragma unroll
        for (int ds = 0; ds < 4; ds++) {
          bf16x8 kf = *(const bf16x8*)(kbase + (t * 32 + lq) * 128 +
                                       ((ds * 32 + hi * 16) ^ lswz));
          sT[t] = __builtin_amdgcn_mfma_f32_32x32x16_bf16(kf, qf[ds], sT[t], 0, 0, 0);
        }
      }
      __builtin_amdgcn_s_setprio(0);

      if (kt * 64 + 63 > wq0) {
#pragma unroll
        for (int t = 0; t < 2; t++)
#pragma unroll
          for (int r = 0; r < 16; r++) {
            int kg = kt * 64 + t * 32 + (r & 3) + 8 * (r >> 2) + 4 * hi;
            if (kg > qg) sT[t][r] = -__builtin_inff();
          }
      }

      float pmax = sT[0][0];
#pragma unroll
      for (int r = 1; r < 16; r++) pmax = fmaxf(pmax, sT[0][r]);
#pragma unroll
      for (int r = 0; r < 16; r++) pmax = fmaxf(pmax, sT[1][r]);
      pmax = fmaxf(pmax, __shfl_xor(pmax, 32, 64));

      if (!__all(pmax <= m_r + 8.f)) {
        float mn = fmaxf(m_r, pmax);
        float scl = __builtin_amdgcn_exp2f(m_r - mn);
        l_r *= scl;
        acc[0] *= scl;
        acc[1] *= scl;
        m_r = mn;
      }

      float ss = 0.f;
#pragma unroll
      for (int t = 0; t < 2; t++)
#pragma unroll
        for (int r = 0; r < 16; r++) {
          float p = __builtin_amdgcn_exp2f(sT[t][r] - m_r);
          sT[t][r] = p;
          ss += p;
        }
      ss += __shfl_xor(ss, 32, 64);
      l_r += ss;

      const char* vbase = (const char*)Vs[b];
#pragma unroll
      for (int t = 0; t < 2; t++) {
        unsigned cp[4][2];
#pragma unroll
        for (int m = 0; m < 4; m++) {
          cp[m][0] = pk2(sT[t][4 * m + 0], sT[t][4 * m + 1]);
          cp[m][1] = pk2(sT[t][4 * m + 2], sT[t][4 * m + 3]);
        }
#pragma unroll
        for (int kl = 0; kl < 2; kl++) {
          unsigned s0 = hi ? cp[2 * kl][0] : cp[2 * kl + 1][0];
          unsigned s1 = hi ? cp[2 * kl][1] : cp[2 * kl + 1][1];
          unsigned r0 = (unsigned)__shfl_xor((int)s0, 32, 64);
          unsigned r1 = (unsigned)__shfl_xor((int)s1, 32, 64);
          union { unsigned u[4]; bf16x8 v; } pa;
          pa.u[0] = hi ? r0 : cp[2 * kl][0];
          pa.u[1] = hi ? r1 : cp[2 * kl][1];
          pa.u[2] = hi ? cp[2 * kl + 1][0] : r0;
          pa.u[3] = hi ? cp[2 * kl + 1][1] : r1;
          int ks = t * 2 + kl;
          __builtin_amdgcn_s_setprio(1);
#pragma unroll
          for (int dt = 0; dt < 2; dt++) {
            bf16x8 vb = *(const bf16x8*)(vbase + (dt * 32 + lq) * 128 +
                                         ((ks * 32 + hi * 16) ^ lswz));
            acc[dt] = __builtin_amdgcn_mfma_f32_32x32x16_bf16(vb, pa.v, acc[dt], 0, 0, 0);
          }
          __builtin_amdgcn_s_setprio(0);
        }
      }
    }

    if (kt + 1 < kt1) {
      *(uint4*)((char*)Ks[b ^ 1] + sd0) = kr0;
      *(uint4*)((char*)Ks[b ^ 1] + sd1) = kr1;
      *(uint4*)((char*)Vs[b ^ 1] + sd0) = vr0;
      *(uint4*)((char*)Vs[b ^ 1] + sd1) = vr1;
    }
    __syncthreads();
  }

  // epilogue: dump raw-lane-layout partial O (bf16 pairs) + (m,l), coalesced
  unsigned* op = Opart + (size_t)c * OCH + ((size_t)(b5 * 4 + w) * 16) * 64;
#pragma unroll
  for (int dt = 0; dt < 2; dt++)
#pragma unroll
    for (int j = 0; j < 8; j++)
      op[(dt * 8 + j) * 64 + l] = pk2(acc[dt][2 * j], acc[dt][2 * j + 1]);
  if (!hi)
    ml[c * (HEADS * SEQ) + h * SEQ + wq0 + lq] = make_float2(m_r, l_r);
}

// ---------- Flash pass 2 (R11 config): merge 2 chunk partials ---------------
__global__ __launch_bounds__(256) void k_merge(const unsigned* __restrict__ Opart,
                                               const float2* __restrict__ ml,
                                               u16* __restrict__ av) {
  __shared__ u16 Ts[8192];  // 16KB: 4 waves x 4KB transpose staging
  int bid = blockIdx.x;
  int h = bid & 31, qblk = bid >> 5;
  int b5 = ((SEQ / 128 - 1 - qblk) << 5) | h;  // pass-1 flat block index
  int tid = threadIdx.x, w = tid >> 6, l = tid & 63;
  int lq = l & 31, hi = l >> 5;
  int wq0 = qblk * 128 + w * 32;

  float2 ml0 = ml[h * SEQ + wq0 + lq];
  float2 ml1 = ml[HEADS * SEQ + h * SEQ + wq0 + lq];
  float m = fmaxf(ml0.x, ml1.x);
  float f0 = __builtin_amdgcn_exp2f(ml0.x - m);
  float f1 = __builtin_amdgcn_exp2f(ml1.x - m);
  float inv = 1.0f / (ml0.y * f0 + ml1.y * f1);

  const unsigned* op0 = Opart + ((size_t)(b5 * 4 + w) * 16) * 64;
  const unsigned* op1 = op0 + OCH;
  f32x16 acc[2];
#pragma unroll
  for (int dt = 0; dt < 2; dt++)
#pragma unroll
    for (int j = 0; j < 8; j++) {
      unsigned a0 = op0[(dt * 8 + j) * 64 + l];
      unsigned a1 = op1[(dt * 8 + j) * 64 + l];
      acc[dt][2 * j] = bflo(a0) * f0 + bflo(a1) * f1;
      acc[dt][2 * j + 1] = bfhi(a0) * f0 + bfhi(a1) * f1;
    }

  // LDS transpose epilogue
  int lswz = (lq & 7) << 4;
  char* wbase = (char*)Ts + w * 4096;
#pragma unroll
  for (int dt = 0; dt < 2; dt++)
#pragma unroll
    for (int m4 = 0; m4 < 4; m4++) {
      int r0 = 4 * m4;
      uint2 pr;
      pr.x = pk2(acc[dt][r0 + 0] * inv, acc[dt][r0 + 1] * inv);
      pr.y = pk2(acc[dt][r0 + 2] * inv, acc[dt][r0 + 3] * inv);
      int byte = lq * 128 + ((dt * 64 + m4 * 16 + hi * 8) ^ lswz);
      *(uint2*)(wbase + byte) = pr;
    }
  __syncthreads();
  int q2 = l >> 1, cH = l & 1;
  int qswz = (q2 & 7) << 4;
#pragma unroll
  for (int i = 0; i < 4; i++) {
    uint4 d = *(const uint4*)(wbase + q2 * 128 + ((cH * 64 + i * 16) ^ qswz));
    *(uint4*)(av + (size_t)(wq0 + q2) * HID + h * HD + cH * 32 + i * 8) = d;
  }
}

extern "C" void kernel_launch(void* const* d_in, const int* in_sizes, int n_in,
                              void* d_out, int out_size, void* d_ws, size_t ws_size,
                              hipStream_t stream) {
  (void)in_sizes; (void)n_in; (void)out_size; (void)ws_size;
  const float* x = (const float*)d_in[0];
  const float* cosp = (const float*)d_in[1];
  const float* sinp = (const float*)d_in[2];
  const float* Wq = (const float*)d_in[3];
  const float* Wk = (const float*)d_in[4];
  const float* Wv = (const float*)d_in[5];
  const float* Wo = (const float*)d_in[6];
  float* out = (float*)d_out;
  char* ws = (char*)d_ws;

  // workspace layout (64 MiB):
  u16* xb = (u16*)(ws);                          // [0,8M)   x bf16; dead after qkv
  float2* mlb = (float2*)(ws);                   // [0,1M)   aliases dead xb (flash2+)
  u16* Wqkv = (u16*)(ws + ((size_t)8 << 20));    // [8,20M)  Wq^T|Wk^T|Wv^T
  u16* WoT = (u16*)(ws + ((size_t)20 << 20));    // [20,28M) Wo^T
  u16* qbuf = (u16*)(ws + ((size_t)28 << 20));   // [28,36M) q rope bf16 [32][S][64]
  u16* kbuf = (u16*)(ws + ((size_t)36 << 20));   // [36,38M) k rope bf16 [8][S][64]
  u16* vtb = (u16*)(ws + ((size_t)38 << 20));    // [38,40M) v^T bf16 [8][64][S]
  u16* av = (u16*)(ws + ((size_t)40 << 20));     // [40,48M) av bf16 [S][2048]
  unsigned* Opart = (unsigned*)(ws + ((size_t)48 << 20));  // [48,64M) 2 chunks x 8M

  k_prep<<<14336, 256, 0, stream>>>(x, Wq, Wk, Wv, Wo, xb, Wqkv, WoT);
  k_gemm_qkv<<<512, 256, 0, stream>>>(xb, Wqkv, cosp, sinp, qbuf, kbuf, vtb);
  k_flash2<<<(SEQ / 128) * HEADS * 2, 256, 0, stream>>>(qbuf, kbuf, vtb, Opart, mlb);
  k_merge<<<(SEQ / 128) * HEADS, 256, 0, stream>>>(Opart, mlb, av);
  k_gemm<<<dim3(SEQ / 128, HID / 128), 256, 0, stream>>>(av, WoT, out, SEQ, HID, HID);
}